// Round 6
// baseline (275.942 us; speedup 1.0000x reference)
//
#include <hip/hip_runtime.h>
#include <math.h>

// PositionFeaturizer on MI355X — round 13:
//  * NEW gemm23: fuses MLP gemm2 (zcat@W_in^T, gelu) + gemm3 (h@W_out^T
//    + bias + x residual) into ONE kernel per 64-row stripe (256 blocks,
//    512 thr, 1/CU). h[64][1024] lives in LDS (128 KB, granule-XOR
//    swizzled) — the 67 MB hbf HBM round-trip and one launch gap are gone.
//    W_in/W_out are B-fragments streamed from L2 into registers (1.2/1 MB,
//    L2-resident, reused by all blocks); zcat A-tiles staged via
//    global_load_lds into a 2x8KB swizzled dbuf. bA/bB two-set prefetch
//    (one kk-step lookahead, ~600 cyc MFMA cover per load at 2 waves/SIMD);
//    sched_barrier(0) pins stage-vs-load issue order so vmcnt(8) provably
//    drains the A-stage. MFMA floor 17.6 us, HBM floor 14 us -> ~25 us
//    replacing gemm2+gemm3 (~60-70 us est).
//  * gemm_nt deleted; everything else unchanged from round 12.

typedef unsigned short u16;
typedef __attribute__((ext_vector_type(8))) short bf16x8;   // 8 bf16 in 4 VGPRs
typedef __attribute__((ext_vector_type(4))) float f32x4;
typedef __attribute__((ext_vector_type(2))) float f32x2;

constexpr int N_NODES = 16384;
constexpr int E_EDGES = 262144;
constexpr int D = 512;
constexpr int KIN = 576;    // 536 padded to 9*64

// workspace layout (bytes)
constexpr size_t OFF_ZATT = 0;                       // 16384*512*2  = 16,777,216
constexpr size_t OFF_ZCAT = 16777216;                // 16384*576*2  = 18,874,368
constexpr size_t OFF_WQK  = 35651584;                // 1024*512*2   = 1,048,576
constexpr size_t OFF_BQK  = 36700160;                // 1024*4       = 4,096
constexpr size_t OFF_WIN  = 36704256;                // 1024*576*2   = 1,179,648
constexpr size_t OFF_WOUT = 37883904;                // 512*1024*2   = 1,048,576
constexpr size_t OFF_QK   = 38932480;                // 16384*1024*1 = 16,777,216 (fp8)
constexpr size_t OFF_BKT  = 55775232;                // 16384*64*4 = 4,194,304
constexpr size_t OFF_REC  = 59969536;                // 262144*64 = 16,777,216
constexpr size_t OFF_CNTP = 93523968;                // 16384*64 = 1,048,576 (padded counters)

static __device__ __forceinline__ u16 f2bf(float f) {
  union { float f; unsigned int u; } v; v.f = f;
  unsigned int u = v.u;
  u = u + 0x7FFFu + ((u >> 16) & 1u);   // RNE
  return (u16)(u >> 16);
}
// async global->LDS, 16 B per lane; LDS dest = wave-uniform base + lane*16
static __device__ __forceinline__ void gload16(const u16* g, u16* l) {
  __builtin_amdgcn_global_load_lds(
      (const __attribute__((address_space(1))) unsigned int*)g,
      (__attribute__((address_space(3))) unsigned int*)l, 16, 0, 0);
}

// ---------------------------------------------------------------- CSR + edge records (1024 blocks)
__global__ __launch_bounds__(256) void prep_edges(
    const int* __restrict__ row_index,
    const float* __restrict__ att_bias, const float* __restrict__ dist,
    const float* __restrict__ src_pos, const int* __restrict__ src_index,
    const int* __restrict__ org_to_src,
    int* __restrict__ cntp, int* __restrict__ bucket, float* __restrict__ rec)
{
  const int gid = blockIdx.x * 256 + threadIdx.x;   // < E_EDGES
  const int r = row_index[gid];
  const int s = src_index[gid];
  const float dv = dist[gid];
  float4 q0, q1, q2, q3;
  q0.x = att_bias[gid];
  q0.y = att_bias[(size_t)1 * E_EDGES + gid];
  q0.z = att_bias[(size_t)2 * E_EDGES + gid];
  q0.w = att_bias[(size_t)3 * E_EDGES + gid];
  q1.x = att_bias[(size_t)4 * E_EDGES + gid];
  q1.y = att_bias[(size_t)5 * E_EDGES + gid];
  q1.z = att_bias[(size_t)6 * E_EDGES + gid];
  q1.w = att_bias[(size_t)7 * E_EDGES + gid];
  q2.x = (dv == 0.f) ? 0.f : 1.f / dv;   // matches ref: inv = 1/dist, then mul
  q2.y = src_pos[(size_t)s * 3 + 0];
  q2.z = src_pos[(size_t)s * 3 + 1];
  q2.w = src_pos[(size_t)s * 3 + 2];
  q3.x = __int_as_float(org_to_src[s]);
  q3.y = 0.f; q3.z = 0.f; q3.w = 0.f;
  float4* rg = (float4*)(rec + (size_t)gid * 16);
  rg[0] = q0; rg[1] = q1; rg[2] = q2; rg[3] = q3;
  const int p = atomicAdd(&cntp[r * 16], 1);   // 1 counter per 64-B line
  if (p < 64) bucket[(size_t)r * 64 + p] = gid;
}

// ---------------------------------------------------------------- weights cast + dual LN
__global__ __launch_bounds__(256) void prep_wln(
    const float* __restrict__ Wq, const float* __restrict__ Wk,
    const float* __restrict__ bq, const float* __restrict__ bk,
    const float* __restrict__ W_in, const float* __restrict__ W_out,
    u16* __restrict__ wqk, float* __restrict__ bqk,
    u16* __restrict__ win, u16* __restrict__ wout,
    const float* __restrict__ x,
    const float* __restrict__ g1, const float* __restrict__ b1,
    const float* __restrict__ g2, const float* __restrict__ b2,
    u16* __restrict__ zatt, u16* __restrict__ zcat)
{
  if (blockIdx.x < 2304) {
    const int gid = blockIdx.x * 256 + threadIdx.x;
    if (gid < 512 * 1024) {
      wqk[gid]  = f2bf(gid < 512 * 512 ? Wq[gid] : Wk[gid - 512 * 512]);
      wout[gid] = f2bf(W_out[gid]);
    }
    if (gid < 1024 * KIN) {
      const int r = gid / KIN, c = gid - r * KIN;
      win[gid] = f2bf(c < 536 ? W_in[r * 536 + c] : 0.f);
    }
    if (gid < 1024) bqk[gid] = gid < 512 ? bq[gid] : bk[gid - 512];
    return;
  }
  // dual layernorm, wave-per-row (4096 blocks x 4 rows)
  const int row = (blockIdx.x - 2304) * 4 + (threadIdx.x >> 6);
  const int l = threadIdx.x & 63;
  const float* xr = x + (size_t)row * D + l * 8;
  const float4 v0 = *(const float4*)(xr);
  const float4 v1 = *(const float4*)(xr + 4);
  float s  = v0.x + v0.y + v0.z + v0.w + v1.x + v1.y + v1.z + v1.w;
  float s2 = v0.x * v0.x + v0.y * v0.y + v0.z * v0.z + v0.w * v0.w
           + v1.x * v1.x + v1.y * v1.y + v1.z * v1.z + v1.w * v1.w;
#pragma unroll
  for (int m = 1; m < 64; m <<= 1) {
    s  += __shfl_xor(s, m, 64);
    s2 += __shfl_xor(s2, m, 64);
  }
  const float mu = s * (1.f / D);
  const float var = s2 * (1.f / D) - mu * mu;
  const float rs = rsqrtf(var + 1e-5f);
  const int c0 = l * 8;
  const float4 ga0 = *(const float4*)(g1 + c0), ga1 = *(const float4*)(g1 + c0 + 4);
  const float4 ba0 = *(const float4*)(b1 + c0), ba1 = *(const float4*)(b1 + c0 + 4);
  const float4 gm0 = *(const float4*)(g2 + c0), gm1 = *(const float4*)(g2 + c0 + 4);
  const float4 bm0 = *(const float4*)(b2 + c0), bm1 = *(const float4*)(b2 + c0 + 4);
  float n[8] = { (v0.x - mu) * rs, (v0.y - mu) * rs, (v0.z - mu) * rs, (v0.w - mu) * rs,
                 (v1.x - mu) * rs, (v1.y - mu) * rs, (v1.z - mu) * rs, (v1.w - mu) * rs };
  const float ga[8] = { ga0.x, ga0.y, ga0.z, ga0.w, ga1.x, ga1.y, ga1.z, ga1.w };
  const float ba[8] = { ba0.x, ba0.y, ba0.z, ba0.w, ba1.x, ba1.y, ba1.z, ba1.w };
  const float gm[8] = { gm0.x, gm0.y, gm0.z, gm0.w, gm1.x, gm1.y, gm1.z, gm1.w };
  const float bm[8] = { bm0.x, bm0.y, bm0.z, bm0.w, bm1.x, bm1.y, bm1.z, bm1.w };
  bf16x8 za, zc;
#pragma unroll
  for (int i = 0; i < 8; ++i) {
    za[i] = (short)f2bf(n[i] * ga[i] + ba[i]);
    zc[i] = (short)f2bf(n[i] * gm[i] + bm[i]);
  }
  *(bf16x8*)(zatt + (size_t)row * D + c0) = za;
  *(bf16x8*)(zcat + (size_t)row * KIN + c0) = zc;
  if (l < 32) ((unsigned int*)(zcat + (size_t)row * KIN + D))[l] = 0;  // feat+pad zero
}

// ---------------------------------------------------------------- 256^2 8-wave deep-pipelined NT GEMM (gemm1 only)
#define MM_BLK(AF, BF, NB) do {                                               \
  __builtin_amdgcn_s_setprio(1);                                              \
  _Pragma("unroll")                                                           \
  for (int mi = 0; mi < 8; ++mi) {                                            \
    acc[mi][NB]     = __builtin_amdgcn_mfma_f32_16x16x32_bf16(AF[mi], BF[0], acc[mi][NB], 0, 0, 0);     \
    acc[mi][NB + 1] = __builtin_amdgcn_mfma_f32_16x16x32_bf16(AF[mi], BF[1], acc[mi][NB + 1], 0, 0, 0); \
  }                                                                           \
  __builtin_amdgcn_s_setprio(0);                                              \
} while (0)

template <int EPI>
__global__ __launch_bounds__(512, 2) void gemm256(
    const u16* __restrict__ A, const u16* __restrict__ B,
    const float* __restrict__ bias,
    void* __restrict__ Cout, int M, int Nn, int K)
{
  extern __shared__ __align__(16) u16 lds[];   // 65536 u16 = 128 KiB
  const int tid = threadIdx.x;
  const int lane = tid & 63;
  const int wave = tid >> 6;          // 0..7
  const int wave_m = wave >> 2;
  const int wave_n = wave & 3;
  const int m0 = blockIdx.x * 256;
  const int n0 = blockIdx.y * 256;
  const int fr = lane & 15;
  const int fq = lane >> 4;
  const int NT = K >> 6;
  const int sw = (fq ^ ((fr >> 1) & 3)) * 8;

  f32x4 acc[8][4];
#pragma unroll
  for (int i = 0; i < 8; ++i)
#pragma unroll
    for (int j = 0; j < 4; ++j) acc[i][j] = 0.f;

  auto stageA = [&](int slot, int ktile, int kh) {
    u16* base = lds + slot * 8192;
    const int kb = ktile * 64 + kh * 32;
#pragma unroll
    for (int r = 0; r < 2; ++r) {
      const int g = r * 512 + tid;
      const int row = g >> 2;
      const int gs = (g & 3) ^ ((row >> 1) & 3);
      gload16(A + (size_t)(m0 + row) * K + kb + gs * 8,
              base + (r * 512 + wave * 64) * 8);
    }
  };
  auto stageB = [&](int slot, int ktile, int kh) {
    u16* base = lds + 32768 + slot * 8192;
    const int kb = ktile * 64 + kh * 32;
#pragma unroll
    for (int r = 0; r < 2; ++r) {
      const int g = r * 512 + tid;
      const int row = g >> 2;
      const int gs = (g & 3) ^ ((row >> 1) & 3);
      gload16(B + (size_t)(n0 + row) * K + kb + gs * 8,
              base + (r * 512 + wave * 64) * 8);
    }
  };
  auto ldA = [&](bf16x8 (&af)[8], int slot) {
    const u16* p = lds + slot * 8192 + (wave_m * 128 + fr) * 32 + sw;
#pragma unroll
    for (int mi = 0; mi < 8; ++mi)
      af[mi] = *(const bf16x8*)(p + mi * 16 * 32);
  };
  auto ldB = [&](bf16x8 (&bf)[2], int slot, int nh) {
    const u16* p = lds + 32768 + slot * 8192 + (wave_n * 64 + nh * 32 + fr) * 32 + sw;
    bf[0] = *(const bf16x8*)(p);
    bf[1] = *(const bf16x8*)(p + 16 * 32);
  };

  stageA(0, 0, 0); stageB(0, 0, 0);
  stageA(1, 0, 1); stageB(1, 0, 1);
  stageA(2, 1, 0); stageB(2, 1, 0);
  stageA(3, 1, 1);
  asm volatile("s_waitcnt vmcnt(10)" ::: "memory");
  __builtin_amdgcn_s_barrier();
  asm volatile("" ::: "memory");

  bf16x8 af[8], bf0[2], bf1[2];
  for (int t = 0; t < NT; ++t) {
    const int sa0 = (2 * t) & 3,  sa1 = (2 * t + 1) & 3;
    const int sb1n = (2 * t + 3) & 3;
    const int t1 = (t + 1 >= NT) ? t + 1 - NT : t + 1;
    const int t2 = (t + 2 >= NT) ? t + 2 - NT : t + 2;

    ldA(af, sa0); ldB(bf0, sa0, 0);
    stageB(sb1n, t1, 1);
    __builtin_amdgcn_s_barrier();
    asm volatile("" ::: "memory");
    MM_BLK(af, bf0, 0);
    __builtin_amdgcn_s_barrier();
    asm volatile("" ::: "memory");
    ldB(bf1, sa0, 1);
    stageA(sa0, t2, 0);
    __builtin_amdgcn_s_barrier();
    asm volatile("" ::: "memory");
    MM_BLK(af, bf1, 2);
    asm volatile("s_waitcnt vmcnt(10)" ::: "memory");
    __builtin_amdgcn_s_barrier();
    asm volatile("" ::: "memory");
    ldA(af, sa1); ldB(bf0, sa1, 0);
    stageB(sa0, t2, 0);
    __builtin_amdgcn_s_barrier();
    asm volatile("" ::: "memory");
    MM_BLK(af, bf0, 0);
    __builtin_amdgcn_s_barrier();
    asm volatile("" ::: "memory");
    ldB(bf1, sa1, 1);
    stageA(sa1, t2, 1);
    __builtin_amdgcn_s_barrier();
    asm volatile("" ::: "memory");
    MM_BLK(af, bf1, 2);
    asm volatile("s_waitcnt vmcnt(10)" ::: "memory");
    __builtin_amdgcn_s_barrier();
    asm volatile("" ::: "memory");
  }
  asm volatile("s_waitcnt vmcnt(0)" ::: "memory");

#pragma unroll
  for (int mi = 0; mi < 8; ++mi) {
#pragma unroll
    for (int nj = 0; nj < 4; ++nj) {
      const int col = n0 + wave_n * 64 + nj * 16 + fr;
      const float bv = bias[col];
#pragma unroll
      for (int rr = 0; rr < 4; ++rr) {
        const int row = m0 + wave_m * 128 + mi * 16 + fq * 4 + rr;
        float v = acc[mi][nj][rr] + bv;
        if (EPI == 1) {
          const float nu = -1.5957691216057308f * (v + 0.044715f * v * v * v);
          const float sg = __builtin_amdgcn_rcpf(1.f + __expf(nu));
          ((u16*)Cout)[(size_t)row * Nn + col] = f2bf(v * sg);
        } else {
          const int pk = __builtin_amdgcn_cvt_pk_fp8_f32(v, v, 0, false);
          ((unsigned char*)Cout)[(size_t)row * Nn + col] = (unsigned char)(pk & 0xFF);
        }
      }
    }
  }
}

// ---------------------------------------------------------------- fused MLP: gemm2 (gelu) + gemm3 (+x residual)
// One block per 64-row stripe (256 blocks, 512 thr, 1 block/CU).
// gemm2: h[64][1024] = gelu(zcat[64][576] @ win^T + b_in); wave w owns cols
//   [128w,128w+128) -> acc[4][8]. A staged via gload16 into swizzled 2x8KB
//   dbuf; B-frags streamed from L2 into regs, bA/bB one-kk-step prefetch.
// h -> LDS [64][1024] bf16, granule^(row&7) swizzle (scalar b16 writes).
// gemm3: out[64][512] = h @ wout^T + b_out + x; wave w owns cols [64w,64w+64)
//   -> o[4][4]. A from swizzled h LDS (2-way, free); B from L2, prefetched.
__global__ __launch_bounds__(512, 2) void gemm23(
    const u16* __restrict__ zcat, const u16* __restrict__ win,
    const float* __restrict__ b_in, const u16* __restrict__ wout,
    const float* __restrict__ b_out, const float* __restrict__ x,
    float* __restrict__ out)
{
  extern __shared__ __align__(16) u16 lds[];   // 8192 (As dbuf) + 65536 (h) u16
  u16* As = lds;                                // 2 slots x [64][64] swizzled
  u16* Hs = lds + 8192;                         // [64][1024] swizzled
  const int tid = threadIdx.x;
  const int lane = tid & 63;
  const int wv = tid >> 6;       // 0..7
  const int fr = lane & 15;
  const int fq = lane >> 4;
  const int m0 = blockIdx.x * 64;

  // ---- gemm2 ----------------------------------------------------
  f32x4 acc[4][8];
#pragma unroll
  for (int i = 0; i < 4; ++i)
#pragma unroll
    for (int j = 0; j < 8; ++j) acc[i][j] = 0.f;

  auto stA = [&](int t, int slot) {            // stage zcat[64][64] tile t
    const int row = tid >> 3, gd = tid & 7;
    const int gs = gd ^ (row & 7);             // inverse-swizzled source granule
    gload16(zcat + (size_t)(m0 + row) * KIN + t * 64 + gs * 8,
            As + slot * 4096 + (wv * 64 + lane) * 8);
  };
  auto ldAfr = [&](int slot, int kk, int mi) -> bf16x8 {
    const int row = mi * 16 + fr;
    const int g = (kk * 4 + fq) ^ (fr & 7);    // swizzled read granule
    return *(const bf16x8*)(As + slot * 4096 + row * 64 + g * 8);
  };
  auto ldBin = [&](int t, int kk, int nj) -> bf16x8 {
    return *(const bf16x8*)(win + (size_t)(wv * 128 + nj * 16 + fr) * KIN
                            + t * 64 + kk * 32 + fq * 8);
  };

  bf16x8 bA[8], bB[8], a2[4];
  stA(0, 0);
#pragma unroll
  for (int nj = 0; nj < 8; ++nj) bA[nj] = ldBin(0, 0, nj);
  asm volatile("s_waitcnt vmcnt(8)" ::: "memory");   // A(0) landed (bA outstanding)
  __builtin_amdgcn_s_barrier();
  asm volatile("" ::: "memory");

#pragma unroll
  for (int t = 0; t < 9; ++t) {
    const int slot = t & 1;
    if (t < 8) stA(t + 1, slot ^ 1);
    __builtin_amdgcn_sched_barrier(0);     // pin: stage issued before reg loads
    // kk = 0: issue B(t,1); compute with bA = B(t,0)
#pragma unroll
    for (int nj = 0; nj < 8; ++nj) bB[nj] = ldBin(t, 1, nj);
#pragma unroll
    for (int mi = 0; mi < 4; ++mi) a2[mi] = ldAfr(slot, 0, mi);
    __builtin_amdgcn_s_setprio(1);
#pragma unroll
    for (int mi = 0; mi < 4; ++mi)
#pragma unroll
      for (int nj = 0; nj < 8; ++nj)
        acc[mi][nj] = __builtin_amdgcn_mfma_f32_16x16x32_bf16(a2[mi], bA[nj], acc[mi][nj], 0, 0, 0);
    __builtin_amdgcn_s_setprio(0);
    // kk = 1: issue B(t+1,0); compute with bB = B(t,1)
    if (t < 8) {
#pragma unroll
      for (int nj = 0; nj < 8; ++nj) bA[nj] = ldBin(t + 1, 0, nj);
    }
#pragma unroll
    for (int mi = 0; mi < 4; ++mi) a2[mi] = ldAfr(slot, 1, mi);
    __builtin_amdgcn_s_setprio(1);
#pragma unroll
    for (int mi = 0; mi < 4; ++mi)
#pragma unroll
      for (int nj = 0; nj < 8; ++nj)
        acc[mi][nj] = __builtin_amdgcn_mfma_f32_16x16x32_bf16(a2[mi], bB[nj], acc[mi][nj], 0, 0, 0);
    __builtin_amdgcn_s_setprio(0);
    if (t < 8) {
      asm volatile("s_waitcnt vmcnt(8)" ::: "memory");  // A(t+1) landed (8 bA in flight)
      __builtin_amdgcn_s_barrier();
      asm volatile("" ::: "memory");
    }
  }

  // ---- gelu -> h in LDS -----------------------------------------
  {
    float bvv[8];
#pragma unroll
    for (int nj = 0; nj < 8; ++nj) bvv[nj] = b_in[wv * 128 + nj * 16 + fr];
#pragma unroll
    for (int mi = 0; mi < 4; ++mi)
#pragma unroll
      for (int nj = 0; nj < 8; ++nj) {
        const int col = wv * 128 + nj * 16 + fr;
        const int colg = col >> 3, cr = col & 7;
#pragma unroll
        for (int rr = 0; rr < 4; ++rr) {
          const int row = mi * 16 + fq * 4 + rr;
          float v = acc[mi][nj][rr] + bvv[nj];
          const float nu = -1.5957691216057308f * (v + 0.044715f * v * v * v);
          const float sg = __builtin_amdgcn_rcpf(1.f + __expf(nu));
          Hs[row * 1024 + ((colg ^ (row & 7)) * 8) + cr] = f2bf(v * sg);
        }
      }
  }
  __syncthreads();

  // ---- gemm3 ----------------------------------------------------
  f32x4 o[4][4];
#pragma unroll
  for (int i = 0; i < 4; ++i)
#pragma unroll
    for (int j = 0; j < 4; ++j) o[i][j] = 0.f;

  auto ldH = [&](int ks, int mi) -> bf16x8 {   // h[mi*16+fr][ks*32+fq*8]
    const int row = mi * 16 + fr;
    const int g = (ks * 4 + fq) ^ (fr & 7);
    return *(const bf16x8*)(Hs + row * 1024 + g * 8);
  };
  auto ldBo = [&](int ks, int nj) -> bf16x8 {
    return *(const bf16x8*)(wout + (size_t)(wv * 64 + nj * 16 + fr) * 1024
                            + ks * 32 + fq * 8);
  };

  bf16x8 oA[4], oB[4], ha[4];
#pragma unroll
  for (int nj = 0; nj < 4; ++nj) oA[nj] = ldBo(0, nj);
#pragma unroll
  for (int ks = 0; ks < 32; ks += 2) {
    // even step: prefetch ks+1, compute with oA
#pragma unroll
    for (int nj = 0; nj < 4; ++nj) oB[nj] = ldBo(ks + 1, nj);
#pragma unroll
    for (int mi = 0; mi < 4; ++mi) ha[mi] = ldH(ks, mi);
    __builtin_amdgcn_s_setprio(1);
#pragma unroll
    for (int mi = 0; mi < 4; ++mi)
#pragma unroll
      for (int nj = 0; nj < 4; ++nj)
        o[mi][nj] = __builtin_amdgcn_mfma_f32_16x16x32_bf16(ha[mi], oA[nj], o[mi][nj], 0, 0, 0);
    __builtin_amdgcn_s_setprio(0);
    // odd step: prefetch ks+2, compute with oB
    if (ks + 2 < 32) {
#pragma unroll
      for (int nj = 0; nj < 4; ++nj) oA[nj] = ldBo(ks + 2, nj);
    }
#pragma unroll
    for (int mi = 0; mi < 4; ++mi) ha[mi] = ldH(ks + 1, mi);
    __builtin_amdgcn_s_setprio(1);
#pragma unroll
    for (int mi = 0; mi < 4; ++mi)
#pragma unroll
      for (int nj = 0; nj < 4; ++nj)
        o[mi][nj] = __builtin_amdgcn_mfma_f32_16x16x32_bf16(ha[mi], oB[nj], o[mi][nj], 0, 0, 0);
    __builtin_amdgcn_s_setprio(0);
  }

  // ---- epilogue: + b_out + x residual ---------------------------
#pragma unroll
  for (int mi = 0; mi < 4; ++mi)
#pragma unroll
    for (int nj = 0; nj < 4; ++nj) {
      const int col = wv * 64 + nj * 16 + fr;
      const float bv = b_out[col];
#pragma unroll
      for (int rr = 0; rr < 4; ++rr) {
        const int row = m0 + mi * 16 + fq * 4 + rr;
        out[(size_t)row * 512 + col] = o[mi][nj][rr] + bv + x[(size_t)row * 512 + col];
      }
    }
}

// ---------------------------------------------------------------- edge pass (bucket CSR + edge records)
// 4-stage pipeline: bucket@i+4, rec@i+3, kv@i+2, compute@i.
__global__ __launch_bounds__(256) void edge_csr(
    const unsigned char* __restrict__ qk8, const float* __restrict__ rec,
    const int* __restrict__ cntp, const int* __restrict__ bucket,
    const float* __restrict__ pos, u16* __restrict__ zcat)
{
  const int lane = threadIdx.x & 63;
  const int wave = threadIdx.x >> 6;
  const int row = blockIdx.x * 4 + wave;
  const int half = lane >> 5;
  const int sub = lane & 31;
  const int h = sub >> 2, j = sub & 3;
  const int deg = min(cntp[row * 16], 64);
  const int base = row * 64;

  const uint4 qv = *(const uint4*)(qk8 + (size_t)row * 1024 + sub * 16);
  float qf[16];
  {
    const unsigned int* qu = (const unsigned int*)&qv;
#pragma unroll
    for (int i = 0; i < 4; ++i) {
      const f32x2 lo = __builtin_amdgcn_cvt_pk_f32_fp8(qu[i], false);
      const f32x2 hi = __builtin_amdgcn_cvt_pk_f32_fp8(qu[i], true);
      qf[i * 4 + 0] = lo.x; qf[i * 4 + 1] = lo.y;
      qf[i * 4 + 2] = hi.x; qf[i * 4 + 3] = hi.y;
    }
  }

  float accA = 0.f, accB = 0.f;
  const int npair = (deg + 1) >> 1;

  bool ok0 = half < deg;
  int e0 = ok0 ? bucket[base + half] : 0;
  const float* r0 = rec + (size_t)e0 * 16;
  float bias0 = r0[h], invd0 = r0[8];
  float spA0 = (j >= 2) ? r0[7 + j] : 0.f;
  float spB0 = (j == 1) ? r0[11] : 0.f;
  uint4 kv0 = *(const uint4*)(qk8 + (size_t)__float_as_int(r0[12]) * 1024 + 512 + sub * 16);

  bool ok1 = 2 + half < deg;
  int e1 = ok1 ? bucket[base + 2 + half] : 0;
  const float* r1 = rec + (size_t)e1 * 16;
  float bias1 = r1[h], invd1 = r1[8];
  float spA1 = (j >= 2) ? r1[7 + j] : 0.f;
  float spB1 = (j == 1) ? r1[11] : 0.f;
  uint4 kv1 = *(const uint4*)(qk8 + (size_t)__float_as_int(r1[12]) * 1024 + 512 + sub * 16);

  bool ok2 = 4 + half < deg;
  int e2 = ok2 ? bucket[base + 4 + half] : 0;
  const float* r2p = rec + (size_t)e2 * 16;
  float bias2 = r2p[h], invd2 = r2p[8];
  float spA2 = (j >= 2) ? r2p[7 + j] : 0.f;
  float spB2 = (j == 1) ? r2p[11] : 0.f;
  int kr2 = __float_as_int(r2p[12]);

  bool ok3 = 6 + half < deg;
  int e3 = ok3 ? bucket[base + 6 + half] : 0;

  for (int i = 0; i < npair; ++i) {
    const uint4 kv2 = *(const uint4*)(qk8 + (size_t)kr2 * 1024 + 512 + sub * 16);
    const float* r3 = rec + (size_t)e3 * 16;
    const float bias3 = r3[h], invd3 = r3[8];
    const float spA3 = (j >= 2) ? r3[7 + j] : 0.f;
    const float spB3 = (j == 1) ? r3[11] : 0.f;
    const int kr3 = __float_as_int(r3[12]);
    const bool ok4 = 2 * (i + 4) + half < deg;
    const int e4 = ok4 ? bucket[base + 2 * (i + 4) + half] : 0;

    float p;
    {
      const unsigned int* ku = (const unsigned int*)&kv0;
      const f32x2 a0 = __builtin_amdgcn_cvt_pk_f32_fp8(ku[0], false);
      const f32x2 a1 = __builtin_amdgcn_cvt_pk_f32_fp8(ku[0], true);
      const f32x2 b0 = __builtin_amdgcn_cvt_pk_f32_fp8(ku[1], false);
      const f32x2 b1 = __builtin_amdgcn_cvt_pk_f32_fp8(ku[1], true);
      const f32x2 c0 = __builtin_amdgcn_cvt_pk_f32_fp8(ku[2], false);
      const f32x2 c1 = __builtin_amdgcn_cvt_pk_f32_fp8(ku[2], true);
      const f32x2 d0 = __builtin_amdgcn_cvt_pk_f32_fp8(ku[3], false);
      const f32x2 d1 = __builtin_amdgcn_cvt_pk_f32_fp8(ku[3], true);
      p = qf[0] * a0.x;
      p = fmaf(qf[1],  a0.y, p);  p = fmaf(qf[2],  a1.x, p);  p = fmaf(qf[3],  a1.y, p);
      p = fmaf(qf[4],  b0.x, p);  p = fmaf(qf[5],  b0.y, p);  p = fmaf(qf[6],  b1.x, p);
      p = fmaf(qf[7],  b1.y, p);  p = fmaf(qf[8],  c0.x, p);  p = fmaf(qf[9],  c0.y, p);
      p = fmaf(qf[10], c1.x, p);  p = fmaf(qf[11], c1.y, p);  p = fmaf(qf[12], d0.x, p);
      p = fmaf(qf[13], d0.y, p);  p = fmaf(qf[14], d1.x, p);  p = fmaf(qf[15], d1.y, p);
    }
    p += __shfl_xor(p, 1, 64);
    p += __shfl_xor(p, 2, 64);
    float pe = __expf(p * 0.125f + bias0);
    pe = ok0 ? pe : 0.f;
    const float w = pe * invd0;
    accA += (j == 0) ? pe : (j == 1) ? w : w * spA0;
    accB += w * spB0;

    ok0 = ok1; bias0 = bias1; invd0 = invd1; spA0 = spA1; spB0 = spB1; kv0 = kv1;
    ok1 = ok2; bias1 = bias2; invd1 = invd2; spA1 = spA2; spB1 = spB2; kv1 = kv2;
    ok2 = ok3; bias2 = bias3; invd2 = invd3; spA2 = spA3; spB2 = spB3; kr2 = kr3;
    ok3 = ok4; e3 = e4;
  }

  accA += __shfl_xor(accA, 32, 64);
  accB += __shfl_xor(accB, 32, 64);
  const int hb = h << 2;
  const float den  = __shfl(accA, hb + 0, 64);
  const float wsum = __shfl(accA, hb + 1, 64);
  const float wsp01 = __shfl(accA, hb + 2 + (j & 1), 64);
  const float wsp2  = __shfl(accB, hb + 1, 64);
  const float invd = (den != 0.f) ? 1.f / den : 0.f;
  const float rsum = wsum * invd;
  if (half == 0 && j < 3) {
    const float wspj = (j < 2) ? wsp01 : wsp2;
    zcat[(size_t)row * KIN + D + h * 3 + j] = f2bf(wspj * invd - rsum * pos[row * 3 + j]);
  }
}

// ---------------------------------------------------------------- launch
extern "C" void kernel_launch(void* const* d_in, const int* in_sizes, int n_in,
                              void* d_out, int out_size, void* d_ws, size_t ws_size,
                              hipStream_t stream)
{
  const float* x        = (const float*)d_in[0];
  const float* Wq       = (const float*)d_in[1];
  const float* bq       = (const float*)d_in[2];
  const float* Wk       = (const float*)d_in[3];
  const float* bk       = (const float*)d_in[4];
  const float* g_att    = (const float*)d_in[5];
  const float* b_att    = (const float*)d_in[6];
  const float* g_mlp    = (const float*)d_in[7];
  const float* b_mlp    = (const float*)d_in[8];
  const float* W_in     = (const float*)d_in[9];
  const float* b_in     = (const float*)d_in[10];
  const float* W_out    = (const float*)d_in[11];
  const float* b_out    = (const float*)d_in[12];
  const float* att_bias = (const float*)d_in[13];
  const float* dist     = (const float*)d_in[14];
  const float* pos      = (const float*)d_in[15];
  const float* src_pos  = (const float*)d_in[16];
  const int* row_index  = (const int*)d_in[17];
  const int* src_index  = (const int*)d_in[18];
  const int* org_to_src = (const int*)d_in[19];

  char* ws = (char*)d_ws;
  u16*   zatt = (u16*)(ws + OFF_ZATT);
  u16*   zcat = (u16*)(ws + OFF_ZCAT);
  u16*   wqk  = (u16*)(ws + OFF_WQK);
  float* bqk  = (float*)(ws + OFF_BQK);
  u16*   win  = (u16*)(ws + OFF_WIN);
  u16*   wout = (u16*)(ws + OFF_WOUT);
  unsigned char* qk8 = (unsigned char*)(ws + OFF_QK);
  int*   bkt  = (int*)(ws + OFF_BKT);
  float* rec  = (float*)(ws + OFF_REC);
  int*   cntp = (int*)(ws + OFF_CNTP);

  static bool s_attr = false;
  if (!s_attr) {
    hipFuncSetAttribute(reinterpret_cast<const void*>(&gemm256<4>),
                        hipFuncAttributeMaxDynamicSharedMemorySize, 131072);
    hipFuncSetAttribute(reinterpret_cast<const void*>(&gemm23),
                        hipFuncAttributeMaxDynamicSharedMemorySize, 147456);
    s_attr = true;
  }

  hipMemsetAsync(ws + OFF_CNTP, 0, 16384 * 64, stream);

  prep_edges<<<E_EDGES / 256, 256, 0, stream>>>(
      row_index, att_bias, dist, src_pos, src_index, org_to_src, cntp, bkt, rec);
  prep_wln<<<2304 + N_NODES / 4, 256, 0, stream>>>(
      Wq, Wk, bq, bk, W_in, W_out, wqk, bqk, win, wout,
      x, g_att, b_att, g_mlp, b_mlp, zatt, zcat);
  gemm256<4><<<dim3(64, 4), 512, 131072, stream>>>(zatt, wqk, bqk, qk8, N_NODES, 1024, 512);
  edge_csr<<<N_NODES / 4, 256, 0, stream>>>(qk8, rec, cntp, bkt, pos, zcat);
  gemm23<<<N_NODES / 64, 512, 147456, stream>>>(zcat, win, b_in, wout, b_out, x, (float*)d_out);
}